// Round 4
// baseline (217.604 us; speedup 1.0000x reference)
//
#include <hip/hip_runtime.h>
#include <hip/hip_fp16.h>
#include <math.h>

#define NB 32
#define NN 512
#define DD 256
#define NROW  (NB*NN)      // 16384 rows per input
#define NELEM (NB*NN*DD)   // 4194304 elements per input

constexpr float INV_EPS   = 10.0f;
constexpr float F_TINY    = 1e-16f;
constexpr float F_NORMEPS = 1e-8f;
constexpr float MARG      = 1.0f / 512.0f;   // a = b = 1/n

// bars layout (ints, 256B padding): per-batch counter at [b*64],
// per-batch release flag at [b*64+16], global tree counter at [2048].
#define BARS_N 2112

typedef __attribute__((ext_vector_type(8))) short bf16x8;
typedef __attribute__((ext_vector_type(4))) float f32x4;

__device__ __forceinline__ unsigned short f2bf(float f) {
    unsigned u = __float_as_uint(f);
    u += 0x7fffu + ((u >> 16) & 1u);          // round-to-nearest-even
    return (unsigned short)(u >> 16);
}

// ---------------------------------------------------------------------------
// Fused: row norms of x,y + bf16 convert + zero cost + zero barrier counters.
// One wave per row (256 floats, float4/lane). 8192 blocks x 256.
// ---------------------------------------------------------------------------
__global__ __launch_bounds__(256) void norms_convert(
        const float* __restrict__ x, const float* __restrict__ y,
        float* __restrict__ nx, float* __restrict__ ny,
        unsigned short* __restrict__ xh, unsigned short* __restrict__ yh,
        float* __restrict__ cost, int* __restrict__ bars) {
    if (blockIdx.x == 0) {
        if (threadIdx.x < NB) cost[threadIdx.x] = 0.0f;
        for (int i = threadIdx.x; i < BARS_N; i += 256) bars[i] = 0;
    }
    int w = threadIdx.x >> 6, l = threadIdx.x & 63;
    int row = blockIdx.x * 4 + w;             // 0..32767
    bool isx = row < NROW;
    int r = isx ? row : row - NROW;
    const float* src = (isx ? x : y) + (size_t)r * DD;
    float4 v = ((const float4*)src)[l];
    float ss = v.x * v.x + v.y * v.y + v.z * v.z + v.w * v.w;
#pragma unroll
    for (int off = 32; off; off >>= 1) ss += __shfl_xor(ss, off);

    unsigned short* ph = (isx ? xh : yh) + (size_t)r * DD + l * 4;
    *(ushort4*)ph = make_ushort4(f2bf(v.x), f2bf(v.y), f2bf(v.z), f2bf(v.w));
    if (l == 0) (isx ? nx : ny)[r] = sqrtf(ss);
}

// ---------------------------------------------------------------------------
// C[b,n,m] = 1 - <x_n,y_m>/max(|x_n||y_m|, 1e-8), single bf16 MFMA.
// Fused epilogue also writes E = fp16(exp(-C/eps)).
// 128x128 tile, BK=32, 256 thr. XOR-swizzled LDS.
// ---------------------------------------------------------------------------
__global__ __launch_bounds__(256) void gemm_cos_mfma(
        const unsigned short* __restrict__ xh, const unsigned short* __restrict__ yh,
        const float* __restrict__ nx, const float* __restrict__ ny,
        float* __restrict__ C, __half* __restrict__ Ef) {
    int blk = blockIdx.x;
    int b = blk >> 4, ti = (blk >> 2) & 3, tj = blk & 3;
    __shared__ short Ah[128][32], Bh[128][32];
    const unsigned short* xbh = xh + ((size_t)b * NN + ti * 128) * DD;
    const unsigned short* ybh = yh + ((size_t)b * NN + tj * 128) * DD;
    int t = threadIdx.x, w = t >> 6, l = t & 63;
    int rw = w * 32, q = l >> 4, low = l & 15;

    f32x4 acc[2][8];
#pragma unroll
    for (int i = 0; i < 2; ++i)
#pragma unroll
        for (int j = 0; j < 8; ++j) acc[i][j] = (f32x4){0.f, 0.f, 0.f, 0.f};

    int sr = t >> 1, h = t & 1;               // staging: 2 threads/row
    int c0i = 2 * h, c1i = 2 * h + 1;         // logical 16B chunks
    int sw0 = (c0i ^ ((sr >> 1) & 3)) * 8;    // swizzled short offsets
    int sw1 = (c1i ^ ((sr >> 1) & 3)) * 8;

    for (int k0 = 0; k0 < DD; k0 += 32) {
        {
            const int4* ga = (const int4*)(xbh + (size_t)sr * DD + k0);
            const int4* gc = (const int4*)(ybh + (size_t)sr * DD + k0);
            int4 a0 = ga[c0i], a1 = ga[c1i];
            int4 c0 = gc[c0i], c1 = gc[c1i];
            *(int4*)&Ah[sr][sw0] = a0; *(int4*)&Ah[sr][sw1] = a1;
            *(int4*)&Bh[sr][sw0] = c0; *(int4*)&Bh[sr][sw1] = c1;
        }
        __syncthreads();

        bf16x8 ah[2];
#pragma unroll
        for (int ti2 = 0; ti2 < 2; ++ti2) {
            int m = rw + ti2 * 16 + low;
            int pq = (q ^ ((m >> 1) & 3)) * 8;
            ah[ti2] = *(const bf16x8*)&Ah[m][pq];
        }
#pragma unroll
        for (int tj2 = 0; tj2 < 8; ++tj2) {
            int n = tj2 * 16 + low;
            int pq = (q ^ ((n >> 1) & 3)) * 8;
            bf16x8 bh = *(const bf16x8*)&Bh[n][pq];
#pragma unroll
            for (int ti2 = 0; ti2 < 2; ++ti2)
                acc[ti2][tj2] = __builtin_amdgcn_mfma_f32_16x16x32_bf16(
                    ah[ti2], bh, acc[ti2][tj2], 0, 0, 0);
        }
        __syncthreads();
    }

    // epilogue: C/D layout col=lane&15, row=(lane>>4)*4+reg  [m89-corrected]
    float*  Cb = C  + (size_t)b * NN * NN;
    __half* Eb = Ef + (size_t)b * NN * NN;
#pragma unroll
    for (int ti2 = 0; ti2 < 2; ++ti2) {
#pragma unroll
        for (int tj2 = 0; tj2 < 8; ++tj2) {
            int gm0 = ti * 128 + rw + ti2 * 16 + q * 4;
            int gn  = tj * 128 + tj2 * 16 + low;
            float nyc = ny[b * NN + gn];
            f32x4 a = acc[ti2][tj2];
#pragma unroll
            for (int reg = 0; reg < 4; ++reg) {
                int gm = gm0 + reg;
                float d = 1.0f - a[reg] / fmaxf(nx[b * NN + gm] * nyc, F_NORMEPS);
                Cb[(size_t)gm * NN + gn] = d;
                Eb[(size_t)gm * NN + gn] = __float2half(__expf(-INV_EPS * d));
            }
        }
    }
}

// ---------------------------------------------------------------------------
// Fully fused Sinkhorn, R4: batch-pair interleave to hide barrier latency.
// 256 blocks x 512 thr (cooperative). Block (xcd, o, p) owns 32-row stripe o
// (0..15) of TWO batches b1=xcd+16p, b2=b1+8 — all 16 stripe blocks of a
// batch share blk&7 -> same XCD L2. Per iteration, each batch's barrier has
// the other batch's full compute phase to settle; only residual skew exposed.
// E stripes in LDS fp16 (2x32KB); sW/sWP shared between phases (transient,
// barrier-ordered); per-batch state (Br,A,Pr) statically indexed via
// unrolled s-loop (rule #20: no runtime-indexed register arrays).
// ---------------------------------------------------------------------------
__global__ __launch_bounds__(512, 2) void sink_fused(
        const __half* __restrict__ Ef, const float* __restrict__ C,
        float* __restrict__ cp0, float* __restrict__ cp1,
        float* __restrict__ pi, float* __restrict__ cost,
        int* __restrict__ bars) {
    int blk = blockIdx.x;
    int xcd = blk & 7, j = blk >> 3;
    int o = j & 15;                       // stripe slot 0..15 (32 rows)
    int p = j >> 4;                       // batch-pair slot 0..1
    int b1 = xcd + 16 * p;                // first batch of pair
    int b2 = b1 + 8;                      // second batch (same XCD set)
    int tt = threadIdx.x, w = tt >> 6, l = tt & 63;
    int* gcnt = &bars[2048];              // global tree counter

    __shared__ __half sE[2][32][NN];      // E stripes, fp16 (64 KB)
    __shared__ float sW[NN];              // w_m (shared between phases)
    __shared__ float sWP[8][NN];          // per-wave column partials (shared)
    __shared__ float sQ[2][NN];           // per-batch Q for pi phase
    __shared__ float sPart[8];

    // ---- stage both E stripes into LDS once: thread (w,l) owns rows
    //      w*4+i (i=0..3), cols 8l..8l+7 (one int4 per row per batch)
#pragma unroll
    for (int s = 0; s < 2; ++s) {
        int bb = s ? b2 : b1;
        const __half* Eb = Ef + ((size_t)bb * NN + o * 32 + w * 4) * NN + 8 * l;
#pragma unroll
        for (int i = 0; i < 4; ++i) {
            int4 raw = *(const int4*)(Eb + (size_t)i * NN);
            *(int4*)&sE[s][w * 4 + i][8 * l] = raw;
        }
    }

    float Br[2] = { 1.0f, 1.0f };
    float A[2][4], Pr[2][4];
#pragma unroll
    for (int s = 0; s < 2; ++s)
#pragma unroll
        for (int i = 0; i < 4; ++i) { A[s][i] = 1.0f; Pr[s][i] = 0.0f; }

    float* cpr = cp0;                     // read buffer
    float* cpw = cp1;                     // iter 1 writes cp1

    for (int t = 1; t <= 15; ++t) {
#pragma unroll
        for (int s = 0; s < 2; ++s) {
            int bb = s ? b2 : b1;
            int* bcnt = &bars[bb * 64];   // padded per-batch counter line

            // ---- wait for prev-iter arrivals of this batch (hidden behind
            //      the other batch's compute phase)
            if (t > 1) {
                if (tt == 0) {
                    while (__hip_atomic_load(bcnt, __ATOMIC_RELAXED,
                                             __HIP_MEMORY_SCOPE_AGENT) < 16 * (t - 1))
                        __builtin_amdgcn_s_sleep(1);
                }
                __syncthreads();
            }

            // ---- step 1: finish v_{t-1}; t==1 has v_0=1, B_0=1
            if (t == 1) {
                sW[tt] = 1.0f;
            } else {
                float sv = 0.0f;
#pragma unroll
                for (int k = 0; k < 16; ++k)
                    sv += __hip_atomic_load(
                        &cpr[(size_t)(bb * 16 + k) * NN + tt],
                        __ATOMIC_RELAXED, __HIP_MEMORY_SCOPE_AGENT);
                float vv = MARG / (Br[s] * sv + F_TINY);
                Br[s] *= vv;               // B_{t-1}
                sW[tt] = Br[s] * vv;       // w_m
            }
            __syncthreads();              // sW ready

            // ---- own 4x8 E tile (raw fp16) + w fragment
            int4 raw[4];
#pragma unroll
            for (int i = 0; i < 4; ++i)
                raw[i] = *(const int4*)&sE[s][w * 4 + i][8 * l];
            float wr[8];
            *(float4*)&wr[0] = *(const float4*)&sW[8 * l];
            *(float4*)&wr[4] = *(const float4*)&sW[8 * l + 4];

            // ---- step 2: u for own 4 rows
#pragma unroll
            for (int i = 0; i < 4; ++i) {
                const __half* hv = (const __half*)&raw[i];
                float sacc = 0.0f;
#pragma unroll
                for (int e = 0; e < 8; ++e)
                    sacc = fmaf(__half2float(hv[e]), wr[e], sacc);
#pragma unroll
                for (int off = 32; off; off >>= 1) sacc += __shfl_xor(sacc, off);
                float uu = MARG / (A[s][i] * sacc + F_TINY);
                A[s][i] *= uu;
                if (t == 15) Pr[s][i] = A[s][i] * uu;  // P = A_15 * u_15
            }

            // ---- step 3: column partials over own stripe with A_t
            float pp[8];
#pragma unroll
            for (int e = 0; e < 8; ++e) pp[e] = 0.0f;
#pragma unroll
            for (int i = 0; i < 4; ++i) {
                const __half* hv = (const __half*)&raw[i];
#pragma unroll
                for (int e = 0; e < 8; ++e)
                    pp[e] = fmaf(__half2float(hv[e]), A[s][i], pp[e]);
            }
            *(float4*)&sWP[w][8 * l]     = make_float4(pp[0], pp[1], pp[2], pp[3]);
            *(float4*)&sWP[w][8 * l + 4] = make_float4(pp[4], pp[5], pp[6], pp[7]);
            __syncthreads();
            float cs = 0.0f;
#pragma unroll
            for (int ww = 0; ww < 8; ++ww) cs += sWP[ww][tt];
            cpw[(size_t)(bb * 16 + o) * NN + tt] = cs;

            // ---- arrive (no wait): __syncthreads drains vmcnt first
            __syncthreads();
            if (tt == 0)
                __hip_atomic_fetch_add(bcnt, 1, __ATOMIC_RELAXED,
                                       __HIP_MEMORY_SCOPE_AGENT);
        }
        float* tmp = cpr; cpr = cpw; cpw = tmp;   // swap once per iteration
    }

    // ---- wait for ALL iter-15 arrivals (both batches), then Q vectors
    if (tt == 0) {
        int* bc = &bars[b1 * 64];
        while (__hip_atomic_load(bc, __ATOMIC_RELAXED,
                                 __HIP_MEMORY_SCOPE_AGENT) < 240)
            __builtin_amdgcn_s_sleep(1);
    } else if (tt == 1) {
        int* bc = &bars[b2 * 64];
        while (__hip_atomic_load(bc, __ATOMIC_RELAXED,
                                 __HIP_MEMORY_SCOPE_AGENT) < 240)
            __builtin_amdgcn_s_sleep(1);
    }
    __syncthreads();
#pragma unroll
    for (int s = 0; s < 2; ++s) {
        int bb = s ? b2 : b1;
        float sv = 0.0f;
#pragma unroll
        for (int k = 0; k < 16; ++k)
            sv += __hip_atomic_load(
                &cpr[(size_t)(bb * 16 + k) * NN + tt],   // cp_15
                __ATOMIC_RELAXED, __HIP_MEMORY_SCOPE_AGENT);
        float vv = MARG / (Br[s] * sv + F_TINY);          // Br = B_14
        sQ[s][tt] = Br[s] * vv * vv;      // Q_m = B_15 * v_15
    }

    // ---- grid barrier (2-level tree): cp scratch aliases pi rows; all cp
    //      reads must finish before ANY block writes pi. (Anti-dep only.)
    //      Thread 0 runs b1's chain, thread 1 runs b2's (divergent-serial).
    __syncthreads();                      // all cp reads done block-wide
    if (tt < 2) {
        int bb = tt ? b2 : b1;
        int* bc  = &bars[bb * 64];
        int* brl = &bars[bb * 64 + 16];
        __hip_atomic_fetch_add(bc, 1, __ATOMIC_RELAXED,
                               __HIP_MEMORY_SCOPE_AGENT);   // reaches 256
        if (o == 0) {
            while (__hip_atomic_load(bc, __ATOMIC_RELAXED,
                                     __HIP_MEMORY_SCOPE_AGENT) < 256)
                __builtin_amdgcn_s_sleep(1);
            __hip_atomic_fetch_add(gcnt, 1, __ATOMIC_RELAXED,
                                   __HIP_MEMORY_SCOPE_AGENT);  // 32 leaders
            while (__hip_atomic_load(gcnt, __ATOMIC_RELAXED,
                                     __HIP_MEMORY_SCOPE_AGENT) < 32)
                __builtin_amdgcn_s_sleep(1);
            __hip_atomic_store(brl, 1, __ATOMIC_RELAXED,
                               __HIP_MEMORY_SCOPE_AGENT);
        } else {
            while (__hip_atomic_load(brl, __ATOMIC_RELAXED,
                                     __HIP_MEMORY_SCOPE_AGENT) == 0)
                __builtin_amdgcn_s_sleep(1);
        }
    }
    __syncthreads();

    // ---- pi phase: identical math to verified pi_cost (f32 C, __expf)
#pragma unroll
    for (int s = 0; s < 2; ++s) {
        int bb = s ? b2 : b1;
        float q0[8];
        *(float4*)&q0[0] = *(const float4*)&sQ[s][4 * l];
        *(float4*)&q0[4] = *(const float4*)&sQ[s][256 + 4 * l];
        const float* Cb = C + (size_t)bb * NN * NN;
        float* pib = pi + (size_t)bb * NN * NN;
        float csum = 0.0f;
#pragma unroll 1
        for (int i = 0; i < 4; ++i) {
            int r = o * 32 + w * 4 + i;
            float pf = Pr[s][i];
            const float* crow = Cb + (size_t)r * NN;
            float* prow = pib + (size_t)r * NN;
            float4 c0 = *(const float4*)(crow + 4 * l);
            float4 c1 = *(const float4*)(crow + 256 + 4 * l);
            float pv0 = pf * q0[0] * __expf(-INV_EPS * c0.x);
            float pv1 = pf * q0[1] * __expf(-INV_EPS * c0.y);
            float pv2 = pf * q0[2] * __expf(-INV_EPS * c0.z);
            float pv3 = pf * q0[3] * __expf(-INV_EPS * c0.w);
            float pv4 = pf * q0[4] * __expf(-INV_EPS * c1.x);
            float pv5 = pf * q0[5] * __expf(-INV_EPS * c1.y);
            float pv6 = pf * q0[6] * __expf(-INV_EPS * c1.z);
            float pv7 = pf * q0[7] * __expf(-INV_EPS * c1.w);
            *(float4*)(prow + 4 * l)       = make_float4(pv0, pv1, pv2, pv3);
            *(float4*)(prow + 256 + 4 * l) = make_float4(pv4, pv5, pv6, pv7);
            csum = fmaf(pv0, c0.x, csum); csum = fmaf(pv1, c0.y, csum);
            csum = fmaf(pv2, c0.z, csum); csum = fmaf(pv3, c0.w, csum);
            csum = fmaf(pv4, c1.x, csum); csum = fmaf(pv5, c1.y, csum);
            csum = fmaf(pv6, c1.z, csum); csum = fmaf(pv7, c1.w, csum);
        }
#pragma unroll
        for (int off = 32; off; off >>= 1) csum += __shfl_xor(csum, off);
        if (l == 0) sPart[w] = csum;
        __syncthreads();
        if (tt == 0) {
            float tot = 0.0f;
#pragma unroll
            for (int ww = 0; ww < 8; ++ww) tot += sPart[ww];
            atomicAdd(&cost[bb], tot);
        }
        __syncthreads();                  // sPart reused by next s
    }
}

// ---------------------------------------------------------------------------
extern "C" void kernel_launch(void* const* d_in, const int* in_sizes, int n_in,
                              void* d_out, int out_size, void* d_ws, size_t ws_size,
                              hipStream_t stream) {
    const float* x = (const float*)d_in[0];
    const float* y = (const float*)d_in[1];
    float* out  = (float*)d_out;
    float* cost = out;                                   // [32]
    float* pi   = out + 32;                              // [32*512*512]
    float* C    = out + 32 + (size_t)NB * NN * NN;       // [32*512*512]

    float* ws = (float*)d_ws;
    float* nx = ws;                    // 16384
    float* ny = ws + 16384;            // 16384
    int* bars = (int*)(ws + 32768);    // padded barrier lines (BARS_N ints)

    // pi region reuse (33.55 MB):
    //   [xh: 8.4 MB][yh: 8.4 MB][Ef16: 16.8 MB]
    // xh/yh dead after gemm; cp double-buffer (2 MB: 32 batches x 16 stripes
    // x 512 floats x 2) lives in xh region. pi itself rewritten only at the
    // very end (after the grid barrier).
    unsigned short* xh = (unsigned short*)pi;
    unsigned short* yh = xh + NELEM;
    __half* Ef = (__half*)(yh + NELEM);
    float* cp0 = pi;
    float* cp1 = pi + (size_t)NB * 16 * NN;

    norms_convert<<<dim3(8192), dim3(256), 0, stream>>>(
        x, y, nx, ny, xh, yh, cost, bars);
    gemm_cos_mfma<<<dim3(512), dim3(256), 0, stream>>>(
        xh, yh, nx, ny, C, Ef);

    const __half* Ef_p = Ef; const float* C_p = C;
    float* cp0_p = cp0; float* cp1_p = cp1;
    float* pi_p = pi; float* cost_p = cost; int* bars_p = bars;
    void* args[] = { &Ef_p, &C_p, &cp0_p, &cp1_p, &pi_p, &cost_p, &bars_p };
    hipLaunchCooperativeKernel(reinterpret_cast<void*>(sink_fused),
                               dim3(256), dim3(512), args, 0, stream);
}

// Round 5
// 183.729 us; speedup vs baseline: 1.1844x; 1.1844x over previous
//
#include <hip/hip_runtime.h>
#include <hip/hip_fp16.h>
#include <math.h>

#define NB 32
#define NN 512
#define DD 256
#define NROW  (NB*NN)      // 16384 rows per input
#define NELEM (NB*NN*DD)   // 4194304 elements per input

constexpr float INV_EPS   = 10.0f;
constexpr float F_TINY    = 1e-16f;
constexpr float F_NORMEPS = 1e-8f;
constexpr float MARG      = 1.0f / 512.0f;   // a = b = 1/n

// bars: one 256B line per batch; ints [b*64 + o] (o=0..7) hold the last
// completed iteration of stripe o of batch b (monotonic flags, no RMW).
#define BARS_N 2048

typedef __attribute__((ext_vector_type(8))) short bf16x8;
typedef __attribute__((ext_vector_type(4))) float f32x4;

__device__ __forceinline__ unsigned short f2bf(float f) {
    unsigned u = __float_as_uint(f);
    u += 0x7fffu + ((u >> 16) & 1u);          // round-to-nearest-even
    return (unsigned short)(u >> 16);
}

// ---------------------------------------------------------------------------
// Fused: row norms of x,y + bf16 convert + zero cost + zero barrier flags.
// One wave per row (256 floats, float4/lane). 8192 blocks x 256.
// ---------------------------------------------------------------------------
__global__ __launch_bounds__(256) void norms_convert(
        const float* __restrict__ x, const float* __restrict__ y,
        float* __restrict__ nx, float* __restrict__ ny,
        unsigned short* __restrict__ xh, unsigned short* __restrict__ yh,
        float* __restrict__ cost, int* __restrict__ bars) {
    if (blockIdx.x == 0) {
        if (threadIdx.x < NB) cost[threadIdx.x] = 0.0f;
        for (int i = threadIdx.x; i < BARS_N; i += 256) bars[i] = 0;
    }
    int w = threadIdx.x >> 6, l = threadIdx.x & 63;
    int row = blockIdx.x * 4 + w;             // 0..32767
    bool isx = row < NROW;
    int r = isx ? row : row - NROW;
    const float* src = (isx ? x : y) + (size_t)r * DD;
    float4 v = ((const float4*)src)[l];
    float ss = v.x * v.x + v.y * v.y + v.z * v.z + v.w * v.w;
#pragma unroll
    for (int off = 32; off; off >>= 1) ss += __shfl_xor(ss, off);

    unsigned short* ph = (isx ? xh : yh) + (size_t)r * DD + l * 4;
    *(ushort4*)ph = make_ushort4(f2bf(v.x), f2bf(v.y), f2bf(v.z), f2bf(v.w));
    if (l == 0) (isx ? nx : ny)[r] = sqrtf(ss);
}

// ---------------------------------------------------------------------------
// C[b,n,m] = 1 - <x_n,y_m>/max(|x_n||y_m|, 1e-8), single bf16 MFMA.
// Fused epilogue also writes E = fp16(exp(-C/eps)).
// 128x128 tile, BK=32, 256 thr. XOR-swizzled LDS.
// ---------------------------------------------------------------------------
__global__ __launch_bounds__(256) void gemm_cos_mfma(
        const unsigned short* __restrict__ xh, const unsigned short* __restrict__ yh,
        const float* __restrict__ nx, const float* __restrict__ ny,
        float* __restrict__ C, __half* __restrict__ Ef) {
    int blk = blockIdx.x;
    int b = blk >> 4, ti = (blk >> 2) & 3, tj = blk & 3;
    __shared__ short Ah[128][32], Bh[128][32];
    const unsigned short* xbh = xh + ((size_t)b * NN + ti * 128) * DD;
    const unsigned short* ybh = yh + ((size_t)b * NN + tj * 128) * DD;
    int t = threadIdx.x, w = t >> 6, l = t & 63;
    int rw = w * 32, q = l >> 4, low = l & 15;

    f32x4 acc[2][8];
#pragma unroll
    for (int i = 0; i < 2; ++i)
#pragma unroll
        for (int j = 0; j < 8; ++j) acc[i][j] = (f32x4){0.f, 0.f, 0.f, 0.f};

    int sr = t >> 1, h = t & 1;               // staging: 2 threads/row
    int c0i = 2 * h, c1i = 2 * h + 1;         // logical 16B chunks
    int sw0 = (c0i ^ ((sr >> 1) & 3)) * 8;    // swizzled short offsets
    int sw1 = (c1i ^ ((sr >> 1) & 3)) * 8;

    for (int k0 = 0; k0 < DD; k0 += 32) {
        {
            const int4* ga = (const int4*)(xbh + (size_t)sr * DD + k0);
            const int4* gc = (const int4*)(ybh + (size_t)sr * DD + k0);
            int4 a0 = ga[c0i], a1 = ga[c1i];
            int4 c0 = gc[c0i], c1 = gc[c1i];
            *(int4*)&Ah[sr][sw0] = a0; *(int4*)&Ah[sr][sw1] = a1;
            *(int4*)&Bh[sr][sw0] = c0; *(int4*)&Bh[sr][sw1] = c1;
        }
        __syncthreads();

        bf16x8 ah[2];
#pragma unroll
        for (int ti2 = 0; ti2 < 2; ++ti2) {
            int m = rw + ti2 * 16 + low;
            int pq = (q ^ ((m >> 1) & 3)) * 8;
            ah[ti2] = *(const bf16x8*)&Ah[m][pq];
        }
#pragma unroll
        for (int tj2 = 0; tj2 < 8; ++tj2) {
            int n = tj2 * 16 + low;
            int pq = (q ^ ((n >> 1) & 3)) * 8;
            bf16x8 bh = *(const bf16x8*)&Bh[n][pq];
#pragma unroll
            for (int ti2 = 0; ti2 < 2; ++ti2)
                acc[ti2][tj2] = __builtin_amdgcn_mfma_f32_16x16x32_bf16(
                    ah[ti2], bh, acc[ti2][tj2], 0, 0, 0);
        }
        __syncthreads();
    }

    // epilogue: C/D layout col=lane&15, row=(lane>>4)*4+reg  [m89-corrected]
    float*  Cb = C  + (size_t)b * NN * NN;
    __half* Eb = Ef + (size_t)b * NN * NN;
#pragma unroll
    for (int ti2 = 0; ti2 < 2; ++ti2) {
#pragma unroll
        for (int tj2 = 0; tj2 < 8; ++tj2) {
            int gm0 = ti * 128 + rw + ti2 * 16 + q * 4;
            int gn  = tj * 128 + tj2 * 16 + low;
            float nyc = ny[b * NN + gn];
            f32x4 a = acc[ti2][tj2];
#pragma unroll
            for (int reg = 0; reg < 4; ++reg) {
                int gm = gm0 + reg;
                float d = 1.0f - a[reg] / fmaxf(nx[b * NN + gm] * nyc, F_NORMEPS);
                Cb[(size_t)gm * NN + gn] = d;
                Eb[(size_t)gm * NN + gn] = __float2half(__expf(-INV_EPS * d));
            }
        }
    }
}

// ---------------------------------------------------------------------------
// Fully fused Sinkhorn, R5 = R3 geometry (64-row stripes, 8 blocks/batch,
// same-XCD) with two sync fixes:
//  - per-batch barrier via 8 per-stripe FLAG words in one 256B line (stores,
//    not RMWs; threads 0-7 poll all 8 flags in one coalesced wave-load).
//    Safety: block overwrites cp buffer (t-1) only after observing all
//    flags >= t, and flag t is stored after that block's read of cp(t-1).
//  - cp/Ef scratch moved to d_ws -> pi is written exactly once at the end,
//    so the R3 grid barrier (cp-aliases-pi anti-dep) is deleted.
// Math/order bit-identical to R3 (absmax must stay 0.0078125).
// ---------------------------------------------------------------------------
__global__ __launch_bounds__(512, 2) void sink_fused(
        const __half* __restrict__ Ef, const float* __restrict__ C,
        float* __restrict__ cp0, float* __restrict__ cp1,
        float* __restrict__ pi, float* __restrict__ cost,
        int* __restrict__ bars) {
    int blk = blockIdx.x;
    int xcd = blk & 7, qq = blk >> 3;
    int o = qq & 7;                       // stripe slot within batch
    int b = ((qq >> 3) << 3) | xcd;       // batch (8 stripes share blk%8/XCD)
    int tt = threadIdx.x, w = tt >> 6, l = tt & 63;
    int* flags = &bars[b * 64];           // 8 per-stripe flags, one line

    __shared__ __half sE[64][NN];         // E stripe, fp16 (64 KB)
    __shared__ float sW[NN];              // w_m (later reused for Q)
    __shared__ float sWP[8][NN];          // per-wave column partials
    __shared__ float sPart[8];

    // ---- stage E stripe into LDS once: thread (w,l) owns rows w*8+i,
    //      cols 8l..8l+7 (one int4 per row)
    {
        const __half* Eb = Ef + ((size_t)b * NN + o * 64 + w * 8) * NN + 8 * l;
#pragma unroll
        for (int i = 0; i < 8; ++i) {
            int4 raw = *(const int4*)(Eb + (size_t)i * NN);
            *(int4*)&sE[w * 8 + i][8 * l] = raw;
        }
    }

    float A[8], Pr[8];
#pragma unroll
    for (int i = 0; i < 8; ++i) { A[i] = 1.0f; Pr[i] = 0.0f; }
    float Br = 1.0f;                      // cumulative col scaling (redundant/block)

    float* cpr = cp0;                     // read buffer
    float* cpw = cp1;                     // iter 1 writes cp1

    for (int t = 1; t <= 15; ++t) {
        // ---- step 1: finish v_{t-1}; t==1 has v_0=1, B_0=1
        if (t == 1) {
            sW[tt] = 1.0f;
        } else {
            // wait: all 8 stripes have completed iteration t-1
            if (tt < 8) {
                while (__hip_atomic_load(&flags[tt], __ATOMIC_RELAXED,
                                         __HIP_MEMORY_SCOPE_AGENT) < t - 1)
                    __builtin_amdgcn_s_sleep(1);
            }
            __syncthreads();
            float sv = 0.0f;
#pragma unroll
            for (int k = 0; k < 8; ++k)
                sv += __hip_atomic_load(
                    &cpr[(size_t)(b * 8 + k) * NN + tt],
                    __ATOMIC_RELAXED, __HIP_MEMORY_SCOPE_AGENT);
            float vv = MARG / (Br * sv + F_TINY);
            Br *= vv;                      // B_{t-1}
            sW[tt] = Br * vv;              // w_m
        }
        __syncthreads();                  // sW ready (and sE on t==1)

        // ---- load own 8x8 E tile from LDS (raw fp16), used by steps 2+3
        int4 raw[8];
#pragma unroll
        for (int i = 0; i < 8; ++i)
            raw[i] = *(const int4*)&sE[w * 8 + i][8 * l];

        float wr[8];
        *(float4*)&wr[0] = *(const float4*)&sW[8 * l];
        *(float4*)&wr[4] = *(const float4*)&sW[8 * l + 4];

        // ---- step 2: u for own 8 rows
#pragma unroll
        for (int i = 0; i < 8; ++i) {
            const __half* hv = (const __half*)&raw[i];
            float s = 0.0f;
#pragma unroll
            for (int e = 0; e < 8; ++e) s = fmaf(__half2float(hv[e]), wr[e], s);
#pragma unroll
            for (int off = 32; off; off >>= 1) s += __shfl_xor(s, off);
            float uu = MARG / (A[i] * s + F_TINY);
            A[i] *= uu;
            if (t == 15) Pr[i] = A[i] * uu;   // P = A_15 * u_15 (all lanes)
        }

        // ---- step 3: column partials over own stripe with A_t
        float p[8];
#pragma unroll
        for (int e = 0; e < 8; ++e) p[e] = 0.0f;
#pragma unroll
        for (int i = 0; i < 8; ++i) {
            const __half* hv = (const __half*)&raw[i];
#pragma unroll
            for (int e = 0; e < 8; ++e)
                p[e] = fmaf(__half2float(hv[e]), A[i], p[e]);
        }
        *(float4*)&sWP[w][8 * l]     = make_float4(p[0], p[1], p[2], p[3]);
        *(float4*)&sWP[w][8 * l + 4] = make_float4(p[4], p[5], p[6], p[7]);
        __syncthreads();
        float cs = 0.0f;
#pragma unroll
        for (int ww = 0; ww < 8; ++ww) cs += sWP[ww][tt];
        cpw[(size_t)(b * 8 + o) * NN + tt] = cs;

        // ---- arrive: syncthreads drains vmcnt (cp stores at L2, L1 is
        //      write-through), then one flag STORE (no RMW chain).
        __syncthreads();
        if (tt == 0)
            __hip_atomic_store(&flags[o], t, __ATOMIC_RELAXED,
                               __HIP_MEMORY_SCOPE_AGENT);

        float* tmp = cpr; cpr = cpw; cpw = tmp;   // swap buffers
    }

    // ---- finish Q: wait for iter-15 flags, then full Q vector per block
    if (tt < 8) {
        while (__hip_atomic_load(&flags[tt], __ATOMIC_RELAXED,
                                 __HIP_MEMORY_SCOPE_AGENT) < 15)
            __builtin_amdgcn_s_sleep(1);
    }
    __syncthreads();
    {
        float sv = 0.0f;
#pragma unroll
        for (int k = 0; k < 8; ++k)
            sv += __hip_atomic_load(
                &cpr[(size_t)(b * 8 + k) * NN + tt],   // cp_15
                __ATOMIC_RELAXED, __HIP_MEMORY_SCOPE_AGENT);
        float vv = MARG / (Br * sv + F_TINY);           // Br = B_14
        sW[tt] = Br * vv * vv;            // Q_m = B_15 * v_15 (reuse sW)
    }
    __syncthreads();                      // Q visible block-wide

    // ---- pi phase: identical math to verified pi_cost (f32 C, __expf).
    //      No grid barrier: cp/Ef live in d_ws, pi is written only here.
    float q0[8];
    *(float4*)&q0[0] = *(const float4*)&sW[4 * l];
    *(float4*)&q0[4] = *(const float4*)&sW[256 + 4 * l];
    const float* Cb = C + (size_t)b * NN * NN;
    float* pib = pi + (size_t)b * NN * NN;
    float csum = 0.0f;
#pragma unroll 1
    for (int i = 0; i < 8; ++i) {
        int r = o * 64 + w * 8 + i;
        float pf = Pr[i];
        const float* crow = Cb + (size_t)r * NN;
        float* prow = pib + (size_t)r * NN;
        float4 c0 = *(const float4*)(crow + 4 * l);
        float4 c1 = *(const float4*)(crow + 256 + 4 * l);
        float pv0 = pf * q0[0] * __expf(-INV_EPS * c0.x);
        float pv1 = pf * q0[1] * __expf(-INV_EPS * c0.y);
        float pv2 = pf * q0[2] * __expf(-INV_EPS * c0.z);
        float pv3 = pf * q0[3] * __expf(-INV_EPS * c0.w);
        float pv4 = pf * q0[4] * __expf(-INV_EPS * c1.x);
        float pv5 = pf * q0[5] * __expf(-INV_EPS * c1.y);
        float pv6 = pf * q0[6] * __expf(-INV_EPS * c1.z);
        float pv7 = pf * q0[7] * __expf(-INV_EPS * c1.w);
        *(float4*)(prow + 4 * l)       = make_float4(pv0, pv1, pv2, pv3);
        *(float4*)(prow + 256 + 4 * l) = make_float4(pv4, pv5, pv6, pv7);
        csum = fmaf(pv0, c0.x, csum); csum = fmaf(pv1, c0.y, csum);
        csum = fmaf(pv2, c0.z, csum); csum = fmaf(pv3, c0.w, csum);
        csum = fmaf(pv4, c1.x, csum); csum = fmaf(pv5, c1.y, csum);
        csum = fmaf(pv6, c1.z, csum); csum = fmaf(pv7, c1.w, csum);
    }
#pragma unroll
    for (int off = 32; off; off >>= 1) csum += __shfl_xor(csum, off);
    if (l == 0) sPart[w] = csum;
    __syncthreads();
    if (tt == 0) {
        float tot = 0.0f;
#pragma unroll
        for (int ww = 0; ww < 8; ++ww) tot += sPart[ww];
        atomicAdd(&cost[b], tot);
    }
}

// ---------------------------------------------------------------------------
extern "C" void kernel_launch(void* const* d_in, const int* in_sizes, int n_in,
                              void* d_out, int out_size, void* d_ws, size_t ws_size,
                              hipStream_t stream) {
    const float* x = (const float*)d_in[0];
    const float* y = (const float*)d_in[1];
    float* out  = (float*)d_out;
    float* cost = out;                                   // [32]
    float* pi   = out + 32;                              // [32*512*512]
    float* C    = out + 32 + (size_t)NB * NN * NN;       // [32*512*512]

    // Workspace layout (all scratch lives in d_ws now; ~35 MB used, d_ws is
    // ~256 MiB per the harness fill size). pi is written exactly once at the
    // end of sink_fused -> no aliasing, no grid barrier.
    float* ws = (float*)d_ws;
    float* nx = ws;                                   // 16384 f
    float* ny = ws + 16384;                           // 16384 f
    int*  bars = (int*)(ws + 32768);                  // 2048 ints (flags)
    unsigned short* xh = (unsigned short*)(ws + 65536);       // 8.39 MB
    unsigned short* yh = xh + NELEM;                          // 8.39 MB
    __half* Ef = (__half*)(yh + NELEM);                       // 16.78 MB
    float* cp0 = (float*)(Ef + (size_t)NB * NN * NN);         // 0.52 MB
    float* cp1 = cp0 + (size_t)NB * 8 * NN;                   // 0.52 MB

    norms_convert<<<dim3(8192), dim3(256), 0, stream>>>(
        x, y, nx, ny, xh, yh, cost, bars);
    gemm_cos_mfma<<<dim3(512), dim3(256), 0, stream>>>(
        xh, yh, nx, ny, C, Ef);

    const __half* Ef_p = Ef; const float* C_p = C;
    float* cp0_p = cp0; float* cp1_p = cp1;
    float* pi_p = pi; float* cost_p = cost; int* bars_p = bars;
    void* args[] = { &Ef_p, &C_p, &cp0_p, &cp1_p, &pi_p, &cost_p, &bars_p };
    hipLaunchCooperativeKernel(reinterpret_cast<void*>(sink_fused),
                               dim3(256), dim3(512), args, 0, stream);
}